// Round 7
// baseline (6768.827 us; speedup 1.0000x reference)
//
#include <hip/hip_runtime.h>
#include <math.h>

#define SEQ 1000
#define IND 76
#define PIDX(i) ((((i)/25)*28) + ((i)%25))   // 25-chunk -> 28-stride padded layout

__device__ __forceinline__ float sigf(float v) { return 1.0f / (1.0f + expf(-v)); }

// w2pk[r][40]: masked branch window of W2 row r (38 cols, zero-padded to 40).
__global__ void pack_w2(const float* __restrict__ W2, float* __restrict__ w2pk) {
    const int i = blockIdx.x * 256 + threadIdx.x;
    if (i >= 400 * 40) return;
    const int r = i / 40, u = i - 40 * r;
    const int col = 38 * (r & 3) + u;
    w2pk[i] = (u < 38 && col < 150) ? W2[r * 150 + col] : 0.f;
}

// wxpk[part][slot][64]: part0 = early (ls cols 100..199), part1 = late (s2 cols 0..99).
// slot s: g=s>>2, c=s&3; rows 2g,2g+1; cols 25c..25c+24. row0 @[0..24], row1 @[28..52].
__global__ void pack_wx(const float* __restrict__ Wx, float* __restrict__ wxpk) {
    const int i = blockIdx.x * 256 + threadIdx.x;
    if (i >= 2 * 200 * 64) return;
    const int p = i / (200 * 64);
    const int rem = i - p * 200 * 64;
    const int s = rem / 64, u = rem - 64 * s;
    const int g = s >> 2, c = s & 3;
    const int j = (u >= 28) ? 1 : 0;
    const int local = u - 28 * j;
    float v = 0.f;
    if (local < 25) {
        const int col = (p == 0 ? 100 : 0) + 25 * c + local;
        v = Wx[(2 * g + j) * 200 + col];
    }
    wxpk[i] = v;
}

// 512 threads, TWO barriers per step (software-pipelined):
//  E t<200:       alpha: stage2-early (wreg[0..99], R6 geometry) + rpart.
//                 beta:  L2(j+1): rows 2t,2t+1 streamed from w2pk; pA,pD=d2; even t owns m2 (pB).
//  L t[200,400):  alpha: dx(j) both halves streamed from wxpk (slot s=t-200) over lsP+s2P.
//                 beta:  stage2-late (wreg[0..99]) + sigmoids + liquid (lanes c<2 own rows).
//  N t[400,500):  alpha: l1_step(j+1) (wreg[0..63], rows 2m,2m+1); even owns m1/s1.
//  S t[500,512):  alpha: x-prefetch issue; beta: x write + readout partials/md (shfl-gathered).
__global__ __launch_bounds__(512) void dhsnn_fwd(
    const float* __restrict__ x,
    const float* __restrict__ W1, const float* __restrict__ b1,
    const float* __restrict__ tau_m1, const float* __restrict__ tau_n1,
    const float* __restrict__ b2, const float* __restrict__ tau_m2,
    const float* __restrict__ tau_n2,
    const float* __restrict__ bxp, const float* __restrict__ bm,
    const float* __restrict__ ba,
    const float* __restrict__ Wm, const float* __restrict__ Wa,
    const float* __restrict__ Wd, const float* __restrict__ bd,
    const float* __restrict__ tau_md,
    const float* __restrict__ w2pk, const float* __restrict__ wxpk,
    float* __restrict__ out)
{
    const int t   = (int)threadIdx.x;
    const int blk = (int)blockIdx.x;

    __shared__ __align__(16) float kin1B[2][128];   // [0..75] xt, [76..125] s1, pad 0 (parity)
    __shared__ __align__(16) float kin2B[2][4][40]; // windows of [s1(50), s2(100)] (parity)
    __shared__ __align__(16) float s2P[112];        // PIDX layout
    __shared__ __align__(16) float dxP[112];
    __shared__ __align__(16) float lsP[112];
    __shared__ __align__(16) float lmP[112];
    __shared__ __align__(16) float lbP[112];
    __shared__ __align__(16) float sEarly[200];
    __shared__ __align__(16) float rpart[200];
    __shared__ float b2S[400], bt2S[400], al2S[100], bmS[100], baS[100], bxS[100];
    __shared__ float wdS[200], b1S[200], bt1S[200], al1S[50];

    // ---- zero LDS ----
    for (int i = t; i < 256; i += 512) (&kin1B[0][0])[i] = 0.f;
    for (int i = t; i < 320; i += 512) (&kin2B[0][0][0])[i] = 0.f;
    for (int i = t; i < 112; i += 512) { s2P[i]=0.f; dxP[i]=0.f; lsP[i]=0.f; lmP[i]=0.f; lbP[i]=0.f; }
    for (int i = t; i < 200; i += 512) { sEarly[i] = 0.f; rpart[i] = 0.f; }
    // ---- scalar tables ----
    if (t < 400) { b2S[t] = b2[t]; bt2S[t] = sigf(tau_n2[t]); }
    if (t < 100) { al2S[t] = sigf(tau_m2[t]); bmS[t] = bm[t]; baS[t] = ba[t]; bxS[t] = bxp[t]; }
    if (t < 200) { wdS[t] = Wd[(t < 100 ? 0 : 100) + (t % 100)];
                   b1S[t] = b1[t]; bt1S[t] = sigf(tau_n1[t]); }
    if (t < 50)  al1S[t] = sigf(tau_m1[t]);

    const int c = t & 3;

    float wreg[100];
    float pA = 0.f, pB = 0.f, pD = 0.f, pS = 0.f;
    float mdA = 0.f, mdB = 0.f;                    // alpha_d / bd (md lanes only)
    float4 xq0 = make_float4(0,0,0,0), xq1 = make_float4(0,0,0,0);

    // ---- weight init ----
    if (t < 400) {
        const bool late = (t >= 200);
        const int  sg   = late ? ((t - 200) >> 2) : (t >> 2);
        const int  colb = (late ? 0 : 100) + 25 * c;
        const int  r0 = 2 * sg, r1 = 2 * sg + 1;
        #pragma unroll
        for (int u = 0; u < 25; ++u) {
            wreg[u]      = Wm[r0 * 200 + colb + u];
            wreg[25 + u] = Wm[r1 * 200 + colb + u];
            wreg[50 + u] = Wa[r0 * 200 + colb + u];
            wreg[75 + u] = Wa[r1 * 200 + colb + u];
        }
    } else if (t < 500) {
        const int m = t - 400;
        const int rA_ = 2 * m, rB_ = 2 * m + 1;
        const int kA = rA_ & 3, kB = rB_ & 3;
        #pragma unroll
        for (int u = 0; u < 32; ++u) {
            const int cA = 32 * kA + u, cB = 32 * kB + u;
            wreg[u]      = (cA < 126) ? W1[rA_ * 126 + cA] : 0.f;
            wreg[32 + u] = (cB < 126) ? W1[rB_ * 126 + cB] : 0.f;
        }
    } else if (t == 508 || t == 509) {
        mdA = sigf(tau_md[t - 508]);
        mdB = bd[t - 508];
    }

    // L1 step: reads kin1B[p] = [xt(k), s1(k-1)]; even threads update m1/s1(k)
    auto l1_step = [&](int p) {
        const int m = t - 400;
        const float* a0p = kin1B[p] + 32 * ((2 * m) & 3);
        const float* a1p = kin1B[p] + 32 * ((2 * m + 1) & 3);
        float acc0 = b1S[2 * m], acc1 = b1S[2 * m + 1];
        #pragma unroll
        for (int u4 = 0; u4 < 8; ++u4) {
            const float4 av = *reinterpret_cast<const float4*>(a0p + 4 * u4);
            acc0 = fmaf(wreg[4*u4+0], av.x, acc0); acc0 = fmaf(wreg[4*u4+1], av.y, acc0);
            acc0 = fmaf(wreg[4*u4+2], av.z, acc0); acc0 = fmaf(wreg[4*u4+3], av.w, acc0);
        }
        #pragma unroll
        for (int u4 = 0; u4 < 8; ++u4) {
            const float4 av = *reinterpret_cast<const float4*>(a1p + 4 * u4);
            acc1 = fmaf(wreg[32+4*u4+0], av.x, acc1); acc1 = fmaf(wreg[32+4*u4+1], av.y, acc1);
            acc1 = fmaf(wreg[32+4*u4+2], av.z, acc1); acc1 = fmaf(wreg[32+4*u4+3], av.w, acc1);
        }
        const float b0 = bt1S[2 * m], b1v = bt1S[2 * m + 1];
        pA = b0 * pA + (1.f - b0) * acc0;
        pD = b1v * pD + (1.f - b1v) * acc1;
        const float pAo = __shfl(pA, (t & 63) | 1, 64);
        const float pDo = __shfl(pD, (t & 63) | 1, 64);
        if ((t & 1) == 0) {
            const float sum = ((pA + pD) + pAo) + pDo;
            const float al = al1S[m >> 1];
            pB = al * pB + (1.f - al) * sum - pS;
            pS = (pB - 1.0f > 0.f) ? 1.f : 0.f;
        }
    };
    // write s1(k) -> kin1B[pk1].s1 and kin2B[pk2].s1win (even N threads)
    auto s1_write = [&](int pk1, int pk2) {
        const int n = (t - 400) >> 1;
        kin1B[pk1][76 + n] = pS;
        const int w = (n >= 38) ? 1 : 0;
        kin2B[pk2][w][n - 38 * w] = pS;
    };

    // L2(k): reads kin2B[p]; writes s2(k) -> s2P + kin2B[p2].s2win
    auto l2_step = [&](int p, int p2) {
        const int r0 = 2 * t, r1 = r0 + 1;
        const float4* w0 = reinterpret_cast<const float4*>(w2pk + r0 * 40);
        const float4* w1 = reinterpret_cast<const float4*>(w2pk + r1 * 40);
        const float* k0 = kin2B[p][r0 & 3];
        const float* k1 = kin2B[p][r1 & 3];
        float a0=0.f, a1=0.f, a2=0.f, a3=0.f;
        #pragma unroll
        for (int cc = 0; cc < 10; ++cc) {
            const float4 wv = w0[cc];
            const float4 av = *reinterpret_cast<const float4*>(k0 + 4 * cc);
            a0 = fmaf(wv.x, av.x, a0); a1 = fmaf(wv.y, av.y, a1);
            a2 = fmaf(wv.z, av.z, a2); a3 = fmaf(wv.w, av.w, a3);
        }
        __builtin_amdgcn_sched_barrier(0);
        float b0=0.f, b1v=0.f, b2v=0.f, b3=0.f;
        #pragma unroll
        for (int cc = 0; cc < 10; ++cc) {
            const float4 wv = w1[cc];
            const float4 av = *reinterpret_cast<const float4*>(k1 + 4 * cc);
            b0 = fmaf(wv.x, av.x, b0); b1v = fmaf(wv.y, av.y, b1v);
            b2v = fmaf(wv.z, av.z, b2v); b3 = fmaf(wv.w, av.w, b3);
        }
        const float proj0 = b2S[r0] + ((a0 + a1) + (a2 + a3));
        const float bt0 = bt2S[r0];
        pA = bt0 * pA + (1.f - bt0) * proj0;
        const float proj1 = b2S[r1] + ((b0 + b1v) + (b2v + b3));
        const float bt1v = bt2S[r1];
        pD = bt1v * pD + (1.f - bt1v) * proj1;
        const float sA = __shfl(pA, (t & 63) | 1, 64);
        const float sD = __shfl(pD, (t & 63) | 1, 64);
        if ((t & 1) == 0) {
            const int q = t >> 1;
            const float sum = ((pA + pD) + sA) + sD;   // ((r0+r1)+r2)+r3
            const float al = al2S[q];
            pB = al * pB + (1.f - al) * sum - s2P[PIDX(q)];
            const float s2n = (pB - 1.0f > 0.f) ? 1.f : 0.f;
            s2P[PIDX(q)] = s2n;
            const int col = 50 + q;
            const int w = (col >= 114) ? 3 : ((col >= 76) ? 2 : 1);
            kin2B[p2][w][col - 38 * w] = s2n;
        }
    };

    __syncthreads();
    // P1: init lb; xt(0) -> kin1B[0]
    if (t < 100) lbP[PIDX(t)] = 1.6f;
    if (t >= 500) {
        const int i0 = t - 500;
        const float* xb = x + (size_t)blk * SEQ * IND;
        *reinterpret_cast<float4*>(&kin1B[0][4 * i0]) =
            *reinterpret_cast<const float4*>(xb + 4 * i0);
        if (i0 < 7)
            *reinterpret_cast<float4*>(&kin1B[0][4 * (i0 + 12)]) =
                *reinterpret_cast<const float4*>(xb + 4 * (i0 + 12));
    }
    __syncthreads();
    // P2: l1_step(0) -> s1(0) into kin1B[1]/kin2B[0]; xt(1) -> kin1B[1]
    if (t >= 400 && t < 500) {
        l1_step(0);
        if ((t & 1) == 0) s1_write(1, 0);
    } else if (t >= 500) {
        const int i0 = t - 500;
        const float* xb = x + ((size_t)blk * SEQ + 1) * IND;
        *reinterpret_cast<float4*>(&kin1B[1][4 * i0]) =
            *reinterpret_cast<const float4*>(xb + 4 * i0);
        if (i0 < 7)
            *reinterpret_cast<float4*>(&kin1B[1][4 * (i0 + 12)]) =
                *reinterpret_cast<const float4*>(xb + 4 * (i0 + 12));
    }
    __syncthreads();
    // P3: L2(0) -> s2(0) into s2P + kin2B[1]
    if (t < 200) l2_step(0, 1);
    __syncthreads();

    for (int j = 0; j < SEQ; ++j) {
        const int pj1 = (j + 1) & 1, pj0 = j & 1;
        // ===== alpha(j) =====
        if (t < 200) {
            {   // stage2-early over lm/lb(j-1)
                const int g = t >> 2;  (void)g;
                const float* apM = lmP + 28 * c;
                const float* apA = lbP + 28 * c;
                float P0=0.f, P1=0.f, P2=0.f, P3=0.f;
                #pragma unroll
                for (int u4 = 0; u4 < 6; ++u4) {
                    const float4 am = *reinterpret_cast<const float4*>(apM + 4 * u4);
                    const float4 aa = *reinterpret_cast<const float4*>(apA + 4 * u4);
                    P0 = fmaf(wreg[   4*u4+0], am.x, P0); P0 = fmaf(wreg[   4*u4+1], am.y, P0);
                    P0 = fmaf(wreg[   4*u4+2], am.z, P0); P0 = fmaf(wreg[   4*u4+3], am.w, P0);
                    P1 = fmaf(wreg[25+4*u4+0], am.x, P1); P1 = fmaf(wreg[25+4*u4+1], am.y, P1);
                    P1 = fmaf(wreg[25+4*u4+2], am.z, P1); P1 = fmaf(wreg[25+4*u4+3], am.w, P1);
                    P2 = fmaf(wreg[50+4*u4+0], aa.x, P2); P2 = fmaf(wreg[50+4*u4+1], aa.y, P2);
                    P2 = fmaf(wreg[50+4*u4+2], aa.z, P2); P2 = fmaf(wreg[50+4*u4+3], aa.w, P2);
                    P3 = fmaf(wreg[75+4*u4+0], aa.x, P3); P3 = fmaf(wreg[75+4*u4+1], aa.y, P3);
                    P3 = fmaf(wreg[75+4*u4+2], aa.z, P3); P3 = fmaf(wreg[75+4*u4+3], aa.w, P3);
                }
                P0 = fmaf(wreg[24], apM[24], P0); P1 = fmaf(wreg[49], apM[24], P1);
                P2 = fmaf(wreg[74], apA[24], P2); P3 = fmaf(wreg[99], apA[24], P3);
                float Q0 = P0 + __shfl_xor(P0, 1, 64), Q1 = P1 + __shfl_xor(P1, 1, 64);
                float Q2 = P2 + __shfl_xor(P2, 1, 64), Q3 = P3 + __shfl_xor(P3, 1, 64);
                float R0 = Q0 + __shfl_xor(Q0, 2, 64), R1 = Q1 + __shfl_xor(Q1, 2, 64);
                float R2 = Q2 + __shfl_xor(Q2, 2, 64), R3 = Q3 + __shfl_xor(Q3, 2, 64);
                sEarly[t] = (c == 0) ? R0 : (c == 1) ? R1 : (c == 2) ? R2 : R3;
            }
            rpart[t] = wdS[t] * lsP[PIDX(t % 100)];
        } else if (t < 400) {
            // dx(j): early half over ls(j-1), late half over s2(j)
            const int s = t - 200, g = s >> 2;
            const float* wEp = wxpk + (size_t)s * 64;
            const float* wLp = wxpk + (size_t)(200 + s) * 64;
            const float* aE = lsP + 28 * c;
            const float* aL = s2P + 28 * c;
            float e0=0.f, e1=0.f;
            #pragma unroll
            for (int u4 = 0; u4 < 6; ++u4) {
                const float4 w0v = *reinterpret_cast<const float4*>(wEp + 4 * u4);
                const float4 w1v = *reinterpret_cast<const float4*>(wEp + 28 + 4 * u4);
                const float4 av  = *reinterpret_cast<const float4*>(aE + 4 * u4);
                e0 = fmaf(w0v.x, av.x, e0); e0 = fmaf(w0v.y, av.y, e0);
                e0 = fmaf(w0v.z, av.z, e0); e0 = fmaf(w0v.w, av.w, e0);
                e1 = fmaf(w1v.x, av.x, e1); e1 = fmaf(w1v.y, av.y, e1);
                e1 = fmaf(w1v.z, av.z, e1); e1 = fmaf(w1v.w, av.w, e1);
            }
            e0 = fmaf(wEp[24], aE[24], e0);
            e1 = fmaf(wEp[52], aE[24], e1);
            __builtin_amdgcn_sched_barrier(0);
            float l0=0.f, l1v=0.f;
            #pragma unroll
            for (int u4 = 0; u4 < 6; ++u4) {
                const float4 w0v = *reinterpret_cast<const float4*>(wLp + 4 * u4);
                const float4 w1v = *reinterpret_cast<const float4*>(wLp + 28 + 4 * u4);
                const float4 av  = *reinterpret_cast<const float4*>(aL + 4 * u4);
                l0 = fmaf(w0v.x, av.x, l0); l0 = fmaf(w0v.y, av.y, l0);
                l0 = fmaf(w0v.z, av.z, l0); l0 = fmaf(w0v.w, av.w, l0);
                l1v = fmaf(w1v.x, av.x, l1v); l1v = fmaf(w1v.y, av.y, l1v);
                l1v = fmaf(w1v.z, av.z, l1v); l1v = fmaf(w1v.w, av.w, l1v);
            }
            l0  = fmaf(wLp[24], aL[24], l0);
            l1v = fmaf(wLp[52], aL[24], l1v);
            float QE0 = e0 + __shfl_xor(e0, 1, 64), QE1 = e1 + __shfl_xor(e1, 1, 64);
            float RE0 = QE0 + __shfl_xor(QE0, 2, 64), RE1 = QE1 + __shfl_xor(QE1, 2, 64);
            float QL0 = l0 + __shfl_xor(l0, 1, 64), QL1 = l1v + __shfl_xor(l1v, 1, 64);
            float RL0 = QL0 + __shfl_xor(QL0, 2, 64), RL1 = QL1 + __shfl_xor(QL1, 2, 64);
            if (c == 0)      dxP[PIDX(2*g)]   = (RL0 + RE0) + bxS[2*g];
            else if (c == 1) dxP[PIDX(2*g+1)] = (RL1 + RE1) + bxS[2*g+1];
        } else if (t < 500) {
            if (j < SEQ - 1) {
                l1_step(pj1);                       // s1(j+1)
                if ((t & 1) == 0) s1_write(pj0, pj1);
            }
        } else {
            if (j + 2 < SEQ) {
                const int i0 = t - 500;
                const float* xb = x + ((size_t)blk * SEQ + (j + 2)) * IND;
                xq0 = *reinterpret_cast<const float4*>(xb + 4 * i0);
                if (i0 < 7) xq1 = *reinterpret_cast<const float4*>(xb + 4 * (i0 + 12));
            }
        }
        __syncthreads();
        // ===== beta(j) =====
        if (t < 200) {
            if (j < SEQ - 1) l2_step(pj1, pj0);     // L2(j+1) -> s2(j+1)
        } else if (t < 400) {
            // stage2-late over dx(j) -> sigmoids -> liquid(j)
            const int s = t - 200, g = s >> 2;
            const float* apD = dxP + 28 * c;
            float P0=0.f, P1=0.f, P2=0.f, P3=0.f;
            #pragma unroll
            for (int u4 = 0; u4 < 6; ++u4) {
                const float4 ad = *reinterpret_cast<const float4*>(apD + 4 * u4);
                P0 = fmaf(wreg[   4*u4+0], ad.x, P0); P0 = fmaf(wreg[   4*u4+1], ad.y, P0);
                P0 = fmaf(wreg[   4*u4+2], ad.z, P0); P0 = fmaf(wreg[   4*u4+3], ad.w, P0);
                P1 = fmaf(wreg[25+4*u4+0], ad.x, P1); P1 = fmaf(wreg[25+4*u4+1], ad.y, P1);
                P1 = fmaf(wreg[25+4*u4+2], ad.z, P1); P1 = fmaf(wreg[25+4*u4+3], ad.w, P1);
                P2 = fmaf(wreg[50+4*u4+0], ad.x, P2); P2 = fmaf(wreg[50+4*u4+1], ad.y, P2);
                P2 = fmaf(wreg[50+4*u4+2], ad.z, P2); P2 = fmaf(wreg[50+4*u4+3], ad.w, P2);
                P3 = fmaf(wreg[75+4*u4+0], ad.x, P3); P3 = fmaf(wreg[75+4*u4+1], ad.y, P3);
                P3 = fmaf(wreg[75+4*u4+2], ad.z, P3); P3 = fmaf(wreg[75+4*u4+3], ad.w, P3);
            }
            P0 = fmaf(wreg[24], apD[24], P0); P1 = fmaf(wreg[49], apD[24], P1);
            P2 = fmaf(wreg[74], apD[24], P2); P3 = fmaf(wreg[99], apD[24], P3);
            float Q0 = P0 + __shfl_xor(P0, 1, 64), Q1 = P1 + __shfl_xor(P1, 1, 64);
            float Q2 = P2 + __shfl_xor(P2, 1, 64), Q3 = P3 + __shfl_xor(P3, 1, 64);
            float R0 = Q0 + __shfl_xor(Q0, 2, 64), R1 = Q1 + __shfl_xor(Q1, 2, 64);
            float R2 = Q2 + __shfl_xor(Q2, 2, 64), R3 = Q3 + __shfl_xor(Q3, 2, 64);
            const float sel  = (c == 0) ? R0 : (c == 1) ? R1 : (c == 2) ? R2 : R3;
            const float bias = (c < 2) ? bmS[2*g + c] : baS[2*g + c - 2];
            const float tv = sigf((sel + sEarly[s]) + bias);
            const int lbase = (t & 63) & ~3;
            const float taP = __shfl(tv, lbase + 2 + (c & 1), 64);
            if (c < 2) {
                const int rq = 2*g + c;
                const float lm = lmP[PIDX(rq)], lb = lbP[PIDX(rq)];
                const float ls = lsP[PIDX(rq)], dxv = dxP[PIDX(rq)];
                const float lbN = taP * lb + (1.f - taP) * ls;
                const float Bv  = 1.6f + 1.8f * lbN;
                const float lmN = lm * tv + (1.f - tv) * dxv - Bv * ls;
                const float lsN = (lmN - Bv > 0.f) ? 1.f : 0.f;
                lmP[PIDX(rq)] = lmN; lbP[PIDX(rq)] = lbN; lsP[PIDX(rq)] = lsN;
            }
        } else if (t >= 500) {
            if (j + 2 < SEQ) {
                const int i0 = t - 500;
                *reinterpret_cast<float4*>(&kin1B[pj0][4 * i0]) = xq0;
                if (i0 < 7) *reinterpret_cast<float4*>(&kin1B[pj0][4 * (i0 + 12)]) = xq1;
            }
            // readout: partial sums on lanes 500-507, shfl-gather on 508/509
            const int rr = t - 500;
            const int rrc = (rr < 8) ? rr : 7;
            float sV = 0.f;
            #pragma unroll
            for (int u = 0; u < 25; ++u) sV += rpart[25 * rrc + u];
            const int o = t - 508;
            const int sb = 52 + 4 * ((o == 1) ? 1 : 0);   // lanes 52..55 or 56..59
            const float v0 = __shfl(sV, sb + 0, 64);
            const float v1 = __shfl(sV, sb + 1, 64);
            const float v2 = __shfl(sV, sb + 2, 64);
            const float v3 = __shfl(sV, sb + 3, 64);
            if ((t == 508 || t == 509) && j >= 1) {
                const float dot = ((v0 + v1) + (v2 + v3)) + mdB;
                pA = mdA * pA + (1.f - mdA) * dot;
                if (j >= 2) pB += pA;
            }
        }
        __syncthreads();
    }

    // ===== epilogue: readout of ls(SEQ-1) =====
    if (t < 200) rpart[t] = wdS[t] * lsP[PIDX(t % 100)];
    __syncthreads();
    if (t >= 500) {
        const int rr = t - 500;
        const int rrc = (rr < 8) ? rr : 7;
        float sV = 0.f;
        #pragma unroll
        for (int u = 0; u < 25; ++u) sV += rpart[25 * rrc + u];
        const int o = t - 508;
        const int sb = 52 + 4 * ((o == 1) ? 1 : 0);
        const float v0 = __shfl(sV, sb + 0, 64);
        const float v1 = __shfl(sV, sb + 1, 64);
        const float v2 = __shfl(sV, sb + 2, 64);
        const float v3 = __shfl(sV, sb + 3, 64);
        if (t == 508 || t == 509) {
            const float dot = ((v0 + v1) + (v2 + v3)) + mdB;
            pA = mdA * pA + (1.f - mdA) * dot;
            pB += pA;
            out[blk * 2 + (t - 508)] = pB;
        }
    }
}

extern "C" void kernel_launch(void* const* d_in, const int* in_sizes, int n_in,
                              void* d_out, int out_size, void* d_ws, size_t ws_size,
                              hipStream_t stream) {
    const float* x      = (const float*)d_in[0];
    const float* W1     = (const float*)d_in[1];
    const float* b1     = (const float*)d_in[2];
    const float* tau_m1 = (const float*)d_in[3];
    const float* tau_n1 = (const float*)d_in[4];
    const float* W2     = (const float*)d_in[5];
    const float* b2     = (const float*)d_in[6];
    const float* tau_m2 = (const float*)d_in[7];
    const float* tau_n2 = (const float*)d_in[8];
    const float* Wx     = (const float*)d_in[9];
    const float* bx     = (const float*)d_in[10];
    const float* Wm     = (const float*)d_in[11];
    const float* bm     = (const float*)d_in[12];
    const float* Wa     = (const float*)d_in[13];
    const float* ba     = (const float*)d_in[14];
    const float* Wd     = (const float*)d_in[15];
    const float* bd     = (const float*)d_in[16];
    const float* tau_md = (const float*)d_in[17];
    float* out  = (float*)d_out;
    float* w2pk = (float*)d_ws;                       // 400*40   = 16000 floats
    float* wxpk = (float*)d_ws + 16000;               // 2*200*64 = 25600 floats

    pack_w2<<<(400 * 40 + 255) / 256, 256, 0, stream>>>(W2, w2pk);
    pack_wx<<<(2 * 200 * 64 + 255) / 256, 256, 0, stream>>>(Wx, wxpk);

    const int batch = in_sizes[0] / (SEQ * IND);      // 256
    dhsnn_fwd<<<batch, 512, 0, stream>>>(x, W1, b1, tau_m1, tau_n1,
                                         b2, tau_m2, tau_n2,
                                         bx, bm, ba, Wm, Wa,
                                         Wd, bd, tau_md,
                                         w2pk, wxpk, out);
}